// Round 16
// baseline (55.511 us; speedup 1.0000x reference)
//
#include <hip/hip_runtime.h>

#define MDIM 4096
#define NDIM 4096
#define NCOEF 768
#define ALPHA 16.0f
#define PANEL_I8 (12 * 16384)      // bytes per 256-row panel (12 K-tiles x 16 KB)

typedef __attribute__((ext_vector_type(4))) int   i32x4;
typedef __attribute__((ext_vector_type(4))) float f32x4;

__device__ __forceinline__ void glds16c(const char* src, char* dst) {
    __builtin_amdgcn_global_load_lds(
        (const __attribute__((address_space(1))) void*)src,
        (__attribute__((address_space(3))) void*)dst, 16, 0, 0);
}

// ---- kernel 0: metadata (r, c, quant scales, dedup, global V-scale) ----
// 12 blocks x 64 (one wave): block b owns p = b*64+lane. maxdw via in-wave
// reduce (each block computes the identical value -> deterministic).
__global__ __launch_bounds__(64) void meta_kernel(
    const int* __restrict__ fidx, const float* __restrict__ dw,
    int* __restrict__ r_m, int* __restrict__ c_m,
    float* __restrict__ suq, float* __restrict__ svq, float* __restrict__ csp)
{
    __shared__ int idx_s[NCOEF];
    const int t = threadIdx.x;
    float m = 0.0f;
    #pragma unroll
    for (int j = 0; j < 12; ++j) {
        idx_s[t + j * 64] = fidx[t + j * 64];
        m = fmaxf(m, fabsf(dw[t + j * 64]));
    }
    #pragma unroll
    for (int off = 32; off > 0; off >>= 1) m = fmaxf(m, __shfl_down(m, off));
    m = __shfl(m, 0);                       // maxdw, all lanes
    __syncthreads();
    const int p = blockIdx.x * 64 + t;
    const int idx = idx_s[p];
    int keep = 1;                           // last write wins
    #pragma unroll 16
    for (int q = 0; q < NCOEF; ++q)
        keep &= (q <= p) | (idx_s[q] != idx);
    const int r = idx >> 12;
    const int c = idx & (NDIM - 1);
    const float s0 = 0.015625f;             // sqrt(1/4096)
    const float s1 = 0.022097086912079612f; // sqrt(2/4096)
    const float Vmax = ALPHA * m * s1;
    const float isV = (Vmax > 0.0f) ? (127.0f / Vmax) : 0.0f;
    r_m[p] = r;
    c_m[p] = c;
    suq[p] = ((r == 0) ? s0 : s1) * (127.0f / s1);
    svq[p] = (float)keep * ALPHA * dw[p] * ((c == 0) ? s0 : s1) * isV;
    if (p == 0) csp[0] = (s1 / 127.0f) * (Vmax / 127.0f);  // CS = sU*sV
}

// ---- kernel 1: materialize U,V as INT8 in panel/chunk layout ----
// chunk = k16*256 + row (16 bytes = 16 consecutive k-values of one row);
// slab (panel,kt) = 16 KB contiguous at (panel*12+kt)*16384. Value:
// round(suq[p] * cos(pi*(2i+1)*f_p/8192)), integer-exact range reduction,
// v_cos in revolutions. Block = (panel,kt,half): thread t = row, 2 k16 each.
__global__ __launch_bounds__(256) void fill_uv(
    const int* __restrict__ r_m, const int* __restrict__ c_m,
    const float* __restrict__ suq, const float* __restrict__ svq,
    char* __restrict__ U8, char* __restrict__ V8)
{
    const int b = blockIdx.x;               // (panel*12 + kt)*2 + half
    const int half = b & 1;
    const int pk = b >> 1;                  // panel*12 + kt
    const int panel = pk / 12;
    const int kt = pk - panel * 12;
    const int t = threadIdx.x;              // row 0..255
    const unsigned tt = 2u * (unsigned)((panel << 8) + t) + 1u;
    const float wrev = 1.0f / 16384.0f;
    #pragma unroll
    for (int cc = 0; cc < 2; ++cc) {
        const int k16 = (half << 1) + cc;
        const int p0 = kt * 64 + (k16 << 4);
        unsigned wu[4] = {0, 0, 0, 0}, wv[4] = {0, 0, 0, 0};
        #pragma unroll
        for (int j = 0; j < 16; ++j) {
            const int p = p0 + j;
            const unsigned nu = (tt * (unsigned)r_m[p]) & 16383u;
            const unsigned nv = (tt * (unsigned)c_m[p]) & 16383u;
            const int qu = (int)rintf(suq[p] * __builtin_amdgcn_cosf((float)nu * wrev));
            const int qv = (int)rintf(svq[p] * __builtin_amdgcn_cosf((float)nv * wrev));
            wu[j >> 2] |= (unsigned)(qu & 255) << ((j & 3) * 8);
            wv[j >> 2] |= (unsigned)(qv & 255) << ((j & 3) * 8);
        }
        const size_t off = ((size_t)pk * 1024 + (size_t)(k16 << 8) + t) << 4;
        *(uint4*)(U8 + off) = make_uint4(wu[0], wu[1], wu[2], wu[3]);
        *(uint4*)(V8 + off) = make_uint4(wv[0], wv[1], wv[2], wv[3]);
    }
}

// ---- kernel 2: out = W + CS * (U8 @ V8^T)  (M=N=4096, K=768, i8->i32) ----
// 256x256 tile, 8 waves (2x4), BK=64 (mfma_i32_16x16x64_i8), 12 K-iters,
// 4 LDS bufs (128 KB), depth-2 prefetch, ONE barrier/iter, counted vmcnt(8).
// i8 halves staging + LDS-read traffic and MFMA time vs bf16. Swapped
// mfma(b,a): lane's 4 acc = 4 consecutive out columns -> float4 epilogue
// via pipelined LDS transpose (proven R10/R15 shape).
__global__ __launch_bounds__(512, 1) void gemm_kernel(
    const float* __restrict__ W,
    const char* __restrict__ U8,
    const char* __restrict__ V8,
    const float* __restrict__ csp,
    float* __restrict__ out)
{
    __shared__ char SM[131072];          // 128 KB
    char* const As = SM;                 // 4 bufs x 16384 B
    char* const Bs = SM + 65536;         // 4 bufs x 16384 B

    const int tid = threadIdx.x;         // 0..511
    const int lane = tid & 63;
    const int wave = tid >> 6;           // 0..7

    // XCD rect swizzle: 256 blocks, 8 XCDs, 4(by) x 8(bx) rect per XCD.
    const int bid = blockIdx.x;
    const int xcd = bid & 7;
    const int local = bid >> 3;
    const int by = ((xcd >> 1) << 2) + (local >> 3);   // 0..15
    const int bx = ((xcd & 1) << 3) + (local & 7);     // 0..15
    const int wr = wave >> 2;            // 0..1
    const int wc = wave & 3;             // 0..3
    const int fr = lane & 15;
    const int fks = lane >> 4;

    const char* uPan = U8 + (size_t)by * PANEL_I8;
    const char* vPan = V8 + (size_t)bx * PANEL_I8;
    const float CS = *csp;

    i32x4 acc[8][4] = {};

    // byte offsets: chunk = fks*256 + row, 16 B each
    const int aO = (fks << 12) + ((wr * 128 + fr) << 4);
    const int bO = (fks << 12) + ((wc * 64 + fr) << 4);

    // epilogue coords
    const int bcol = (bx << 8) + (lane << 2);
    const int erowBase = (by << 8);
    float4 wpre[2][4];

#define STAGE(j, buf) do {                                                  \
        const char* uS = uPan + (size_t)(j) * 16384;                        \
        const char* vS = vPan + (size_t)(j) * 16384;                        \
        glds16c(uS + (tid << 4),        As + (buf) * 16384 + (wave << 10)); \
        glds16c(uS + 8192 + (tid << 4), As + (buf) * 16384 + 8192 + (wave << 10)); \
        glds16c(vS + (tid << 4),        Bs + (buf) * 16384 + (wave << 10)); \
        glds16c(vS + 8192 + (tid << 4), Bs + (buf) * 16384 + 8192 + (wave << 10)); \
    } while (0)

#define COMPUTE(buf) do {                                                   \
        i32x4 a[8], b[4];                                                   \
        _Pragma("unroll")                                                   \
        for (int fm = 0; fm < 8; ++fm)                                      \
            a[fm] = *(const i32x4*)(As + (buf) * 16384 + aO + fm * 256);    \
        _Pragma("unroll")                                                   \
        for (int fn = 0; fn < 4; ++fn)                                      \
            b[fn] = *(const i32x4*)(Bs + (buf) * 16384 + bO + fn * 256);    \
        _Pragma("unroll")                                                   \
        for (int fm = 0; fm < 8; ++fm)                                      \
            _Pragma("unroll")                                               \
            for (int fn = 0; fn < 4; ++fn)                                  \
                acc[fm][fn] = __builtin_amdgcn_mfma_i32_16x16x64_i8(        \
                    b[fn], a[fm], acc[fm][fn], 0, 0, 0);                    \
    } while (0)

#define VW(n) asm volatile("s_waitcnt vmcnt(" #n ")" ::: "memory")

    STAGE(0, 0);
    STAGE(1, 1);
    #pragma unroll
    for (int j = 0; j < 12; ++j) {
        if (j < 10) {
            STAGE(j + 2, (j + 2) & 3);
            VW(8);                       // tile j done; j+1, j+2 in flight
        } else if (j == 10) {
            VW(4);
        } else {
            VW(0);
        }
        __builtin_amdgcn_s_barrier();
        asm volatile("" ::: "memory");
        COMPUTE(j & 3);
    }

    // ---- epilogue: out = W + CS*acc, pipelined LDS transpose ----
    // acc[fm][fn][jj] -> tile[wr*128+fm*16+fr][wc*64+fn*16+fks*4+jj]
    // chunk c: rows 32c..32c+31, owner wr == c>>2, acc pair (c&3)*2.
    // L regions: 32 x 258 f32 at f32 offsets 0 / 8256 (66 KB < 128 KB).
    // Region0 overlaps As bufs 0-2 (dead: last COMPUTE read buf 3);
    // region1 first written after the first __syncthreads -> safe.
    float* const L = (float*)SM;
    #pragma unroll
    for (int i = 0; i < 4; ++i)
        wpre[0][i] = *(const float4*)(
            W + (size_t)(erowBase + wave * 4 + i) * NDIM + bcol);
    if (wr == 0) {
        #pragma unroll
        for (int f2 = 0; f2 < 2; ++f2)
            #pragma unroll
            for (int fn = 0; fn < 4; ++fn) {
                f32x4 v;
                #pragma unroll
                for (int jj = 0; jj < 4; ++jj) v[jj] = CS * (float)acc[f2][fn][jj];
                *(f32x4*)(L + (f2 * 16 + fr) * 258 + wc * 64 + fn * 16 + fks * 4) = v;
            }
    }
    #pragma unroll
    for (int c = 0; c < 8; ++c) {
        __syncthreads();                 // L writes visible; drains vmcnt
        if (c < 7) {
            #pragma unroll
            for (int i = 0; i < 4; ++i)
                wpre[(c + 1) & 1][i] = *(const float4*)(
                    W + (size_t)(erowBase + (c + 1) * 32 + wave * 4 + i) * NDIM + bcol);
            if (wr == ((c + 1) >> 2)) {
                #pragma unroll
                for (int f2 = 0; f2 < 2; ++f2)
                    #pragma unroll
                    for (int fn = 0; fn < 4; ++fn) {
                        f32x4 v;
                        #pragma unroll
                        for (int jj = 0; jj < 4; ++jj)
                            v[jj] = CS * (float)acc[((c + 1) & 3) * 2 + f2][fn][jj];
                        *(f32x4*)(L + ((c + 1) & 1) * 8256
                                  + (f2 * 16 + fr) * 258 + wc * 64 + fn * 16 + fks * 4) = v;
                    }
            }
        }
        #pragma unroll
        for (int i = 0; i < 4; ++i) {
            const int rl2 = wave * 4 + i;
            const size_t o = (size_t)(erowBase + c * 32 + rl2) * NDIM + bcol;
            const f32x4 l4 = *(const f32x4*)(L + (c & 1) * 8256 + rl2 * 258 + (lane << 2));
            float4 r4;
            r4.x = wpre[c & 1][i].x + l4[0];
            r4.y = wpre[c & 1][i].y + l4[1];
            r4.z = wpre[c & 1][i].z + l4[2];
            r4.w = wpre[c & 1][i].w + l4[3];
            *(float4*)(out + o) = r4;
        }
    }
#undef STAGE
#undef COMPUTE
#undef VW
}

extern "C" void kernel_launch(void* const* d_in, const int* in_sizes, int n_in,
                              void* d_out, int out_size, void* d_ws, size_t ws_size,
                              hipStream_t stream) {
    const float* weight = (const float*)d_in[0];
    const float* dw     = (const float*)d_in[1];
    const int*   fidx   = (const int*)d_in[2];
    float* out = (float*)d_out;

    char* ws = (char*)d_ws;
    char* U8 = ws;                               // 3,145,728 B
    char* V8 = ws + 3145728;                     // 3,145,728 B
    char* meta = ws + 2 * 3145728;
    int*   r_m = (int*)(meta);
    int*   c_m = (int*)(meta + NCOEF * 4);
    float* suq = (float*)(meta + NCOEF * 8);
    float* svq = (float*)(meta + NCOEF * 12);
    float* csp = (float*)(meta + NCOEF * 16);

    meta_kernel<<<12, 64, 0, stream>>>(fidx, dw, r_m, c_m, suq, svq, csp);
    fill_uv<<<16 * 12 * 2, 256, 0, stream>>>(r_m, c_m, suq, svq, U8, V8);
    gemm_kernel<<<256, 512, 0, stream>>>(weight, U8, V8, csp, out);
}

// Round 17
// 41.088 us; speedup vs baseline: 1.3510x; 1.3510x over previous
//
#include <hip/hip_runtime.h>

#define MDIM 4096
#define NDIM 4096
#define NCOEF 768
#define ALPHA 16.0f
#define PANEL_I8 (12 * 16384)      // bytes per 256-row panel (12 K-tiles x 16 KB)

typedef __attribute__((ext_vector_type(4))) int   i32x4;
typedef __attribute__((ext_vector_type(4))) float f32x4;

__device__ __forceinline__ void glds16c(const char* src, char* dst) {
    __builtin_amdgcn_global_load_lds(
        (const __attribute__((address_space(1))) void*)src,
        (__attribute__((address_space(3))) void*)dst, 16, 0, 0);
}

// ---- kernel 1: materialize U,V as INT8 in panel/chunk layout (meta fused) ----
// Block b = panel*48 + kt*4 + k16 (768 blocks, 3/CU): covers rows of one
// panel x 16 coefs (p0..p0+15). Self-contained: loads fidx/dw, computes
// maxdw (block reduce), dedup (16 thr/coef x 48 q), scales -> LDS, then
// each thread emits one 16-byte chunk per array (row t, 16 consecutive k).
// cos via v_cos_f32 in revolutions, integer-exact range reduction.
__global__ __launch_bounds__(256) void fill_uv(
    const int* __restrict__ fidx, const float* __restrict__ dw,
    char* __restrict__ U8, char* __restrict__ V8, float* __restrict__ csp)
{
    __shared__ int idx_s[NCOEF];
    __shared__ float red[4];
    __shared__ int dup[16];
    __shared__ float su_l[16], sv_l[16];
    const int b = blockIdx.x;
    const int panel = b / 48;
    const int rem = b - panel * 48;
    const int kt = rem >> 2;
    const int k16 = rem & 3;
    const int p0 = kt * 64 + (k16 << 4);
    const int t = threadIdx.x;
    float m = 0.0f;
    #pragma unroll
    for (int j = 0; j < 3; ++j) {
        idx_s[t + (j << 8)] = fidx[t + (j << 8)];
        m = fmaxf(m, fabsf(dw[t + (j << 8)]));
    }
    if (t < 16) dup[t] = 0;
    #pragma unroll
    for (int off = 32; off > 0; off >>= 1) m = fmaxf(m, __shfl_xor(m, off));
    if ((t & 63) == 0) red[t >> 6] = m;
    __syncthreads();
    const float maxdw = fmaxf(fmaxf(red[0], red[1]), fmaxf(red[2], red[3]));
    {   // dedup (last-write-wins): 16 threads per coef scan 48 q's each
        const int ci = t >> 4;
        const int pci = p0 + ci;
        const int myidx = idx_s[pci];
        const int q0 = (t & 15) * 48;
        int found = 0;
        #pragma unroll
        for (int s = 0; s < 48; ++s) {
            const int q = q0 + s;
            found |= (q > pci) & (idx_s[q] == myidx);
        }
        if (found) dup[ci] = 1;      // benign same-value race
    }
    __syncthreads();
    const float s0 = 0.015625f;                // sqrt(1/4096)
    const float s1 = 0.022097086912079612f;    // sqrt(2/4096)
    const float Vmax = ALPHA * maxdw * s1;
    const float isV = (Vmax > 0.0f) ? (127.0f / Vmax) : 0.0f;
    if (t < 16) {
        const int p = p0 + t;
        const int idx = idx_s[p];
        const int r = idx >> 12;
        const int c = idx & (NDIM - 1);
        su_l[t] = ((r == 0) ? s0 : s1) * (127.0f / s1);
        sv_l[t] = (dup[t] ? 0.0f : 1.0f) * ALPHA * dw[p] * ((c == 0) ? s0 : s1) * isV;
    }
    if (b == 0 && t == 0) csp[0] = (s1 / 127.0f) * (Vmax / 127.0f);  // CS
    __syncthreads();
    const unsigned tt = 2u * (unsigned)((panel << 8) + t) + 1u;
    const float wrev = 1.0f / 16384.0f;
    unsigned wu[4] = {0, 0, 0, 0}, wv[4] = {0, 0, 0, 0};
    #pragma unroll
    for (int j = 0; j < 16; ++j) {
        const int idx = idx_s[p0 + j];          // LDS broadcast
        const unsigned nu = (tt * (unsigned)(idx >> 12)) & 16383u;
        const unsigned nv = (tt * (unsigned)(idx & (NDIM - 1))) & 16383u;
        const int qu = (int)rintf(su_l[j] * __builtin_amdgcn_cosf((float)nu * wrev));
        const int qv = (int)rintf(sv_l[j] * __builtin_amdgcn_cosf((float)nv * wrev));
        wu[j >> 2] |= (unsigned)(qu & 255) << ((j & 3) * 8);
        wv[j >> 2] |= (unsigned)(qv & 255) << ((j & 3) * 8);
    }
    const size_t off = ((size_t)(panel * 12 + kt) * 1024 + (size_t)(k16 << 8) + t) << 4;
    *(uint4*)(U8 + off) = make_uint4(wu[0], wu[1], wu[2], wu[3]);
    *(uint4*)(V8 + off) = make_uint4(wv[0], wv[1], wv[2], wv[3]);
}

// ---- kernel 2: out = W + CS * (U8 @ V8^T)  (M=N=4096, K=768, i8->i32) ----
// Unchanged from R16 (measured 39.5 us warm). 256x256 tile, 8 waves, BK=64
// (mfma_i32_16x16x64_i8), 12 K-iters, 4 LDS bufs, depth-2 prefetch, ONE
// barrier/iter, counted vmcnt(8). Pipelined LDS-transpose epilogue.
__global__ __launch_bounds__(512, 1) void gemm_kernel(
    const float* __restrict__ W,
    const char* __restrict__ U8,
    const char* __restrict__ V8,
    const float* __restrict__ csp,
    float* __restrict__ out)
{
    __shared__ char SM[131072];          // 128 KB
    char* const As = SM;                 // 4 bufs x 16384 B
    char* const Bs = SM + 65536;         // 4 bufs x 16384 B

    const int tid = threadIdx.x;         // 0..511
    const int lane = tid & 63;
    const int wave = tid >> 6;           // 0..7

    // XCD rect swizzle: 256 blocks, 8 XCDs, 4(by) x 8(bx) rect per XCD.
    const int bid = blockIdx.x;
    const int xcd = bid & 7;
    const int local = bid >> 3;
    const int by = ((xcd >> 1) << 2) + (local >> 3);   // 0..15
    const int bx = ((xcd & 1) << 3) + (local & 7);     // 0..15
    const int wr = wave >> 2;            // 0..1
    const int wc = wave & 3;             // 0..3
    const int fr = lane & 15;
    const int fks = lane >> 4;

    const char* uPan = U8 + (size_t)by * PANEL_I8;
    const char* vPan = V8 + (size_t)bx * PANEL_I8;
    const float CS = *csp;

    i32x4 acc[8][4] = {};

    // byte offsets: chunk = fks*256 + row, 16 B each
    const int aO = (fks << 12) + ((wr * 128 + fr) << 4);
    const int bO = (fks << 12) + ((wc * 64 + fr) << 4);

    // epilogue coords
    const int bcol = (bx << 8) + (lane << 2);
    const int erowBase = (by << 8);
    float4 wpre[2][4];

#define STAGE(j, buf) do {                                                  \
        const char* uS = uPan + (size_t)(j) * 16384;                        \
        const char* vS = vPan + (size_t)(j) * 16384;                        \
        glds16c(uS + (tid << 4),        As + (buf) * 16384 + (wave << 10)); \
        glds16c(uS + 8192 + (tid << 4), As + (buf) * 16384 + 8192 + (wave << 10)); \
        glds16c(vS + (tid << 4),        Bs + (buf) * 16384 + (wave << 10)); \
        glds16c(vS + 8192 + (tid << 4), Bs + (buf) * 16384 + 8192 + (wave << 10)); \
    } while (0)

#define COMPUTE(buf) do {                                                   \
        i32x4 a[8], b[4];                                                   \
        _Pragma("unroll")                                                   \
        for (int fm = 0; fm < 8; ++fm)                                      \
            a[fm] = *(const i32x4*)(As + (buf) * 16384 + aO + fm * 256);    \
        _Pragma("unroll")                                                   \
        for (int fn = 0; fn < 4; ++fn)                                      \
            b[fn] = *(const i32x4*)(Bs + (buf) * 16384 + bO + fn * 256);    \
        _Pragma("unroll")                                                   \
        for (int fm = 0; fm < 8; ++fm)                                      \
            _Pragma("unroll")                                               \
            for (int fn = 0; fn < 4; ++fn)                                  \
                acc[fm][fn] = __builtin_amdgcn_mfma_i32_16x16x64_i8(        \
                    b[fn], a[fm], acc[fm][fn], 0, 0, 0);                    \
    } while (0)

#define VW(n) asm volatile("s_waitcnt vmcnt(" #n ")" ::: "memory")

    STAGE(0, 0);
    STAGE(1, 1);
    #pragma unroll
    for (int j = 0; j < 12; ++j) {
        if (j < 10) {
            STAGE(j + 2, (j + 2) & 3);
            VW(8);                       // tile j done; j+1, j+2 in flight
        } else if (j == 10) {
            VW(4);
        } else {
            VW(0);
        }
        __builtin_amdgcn_s_barrier();
        asm volatile("" ::: "memory");
        COMPUTE(j & 3);
    }

    // ---- epilogue: out = W + CS*acc, pipelined LDS transpose ----
    float* const L = (float*)SM;
    #pragma unroll
    for (int i = 0; i < 4; ++i)
        wpre[0][i] = *(const float4*)(
            W + (size_t)(erowBase + wave * 4 + i) * NDIM + bcol);
    if (wr == 0) {
        #pragma unroll
        for (int f2 = 0; f2 < 2; ++f2)
            #pragma unroll
            for (int fn = 0; fn < 4; ++fn) {
                f32x4 v;
                #pragma unroll
                for (int jj = 0; jj < 4; ++jj) v[jj] = CS * (float)acc[f2][fn][jj];
                *(f32x4*)(L + (f2 * 16 + fr) * 258 + wc * 64 + fn * 16 + fks * 4) = v;
            }
    }
    #pragma unroll
    for (int c = 0; c < 8; ++c) {
        __syncthreads();                 // L writes visible; drains vmcnt
        if (c < 7) {
            #pragma unroll
            for (int i = 0; i < 4; ++i)
                wpre[(c + 1) & 1][i] = *(const float4*)(
                    W + (size_t)(erowBase + (c + 1) * 32 + wave * 4 + i) * NDIM + bcol);
            if (wr == ((c + 1) >> 2)) {
                #pragma unroll
                for (int f2 = 0; f2 < 2; ++f2)
                    #pragma unroll
                    for (int fn = 0; fn < 4; ++fn) {
                        f32x4 v;
                        #pragma unroll
                        for (int jj = 0; jj < 4; ++jj)
                            v[jj] = CS * (float)acc[((c + 1) & 3) * 2 + f2][fn][jj];
                        *(f32x4*)(L + ((c + 1) & 1) * 8256
                                  + (f2 * 16 + fr) * 258 + wc * 64 + fn * 16 + fks * 4) = v;
                    }
            }
        }
        #pragma unroll
        for (int i = 0; i < 4; ++i) {
            const int rl2 = wave * 4 + i;
            const size_t o = (size_t)(erowBase + c * 32 + rl2) * NDIM + bcol;
            const f32x4 l4 = *(const f32x4*)(L + (c & 1) * 8256 + rl2 * 258 + (lane << 2));
            float4 r4;
            r4.x = wpre[c & 1][i].x + l4[0];
            r4.y = wpre[c & 1][i].y + l4[1];
            r4.z = wpre[c & 1][i].z + l4[2];
            r4.w = wpre[c & 1][i].w + l4[3];
            *(float4*)(out + o) = r4;
        }
    }
#undef STAGE
#undef COMPUTE
#undef VW
}

extern "C" void kernel_launch(void* const* d_in, const int* in_sizes, int n_in,
                              void* d_out, int out_size, void* d_ws, size_t ws_size,
                              hipStream_t stream) {
    const float* weight = (const float*)d_in[0];
    const float* dw     = (const float*)d_in[1];
    const int*   fidx   = (const int*)d_in[2];
    float* out = (float*)d_out;

    char* ws = (char*)d_ws;
    char* U8 = ws;                               // 3,145,728 B
    char* V8 = ws + 3145728;                     // 3,145,728 B
    float* csp = (float*)(ws + 2 * 3145728);

    fill_uv<<<16 * 48, 256, 0, stream>>>(fidx, dw, U8, V8, csp);
    gemm_kernel<<<256, 512, 0, stream>>>(weight, U8, V8, csp, out);
}